// Round 7
// baseline (4141.455 us; speedup 1.0000x reference)
//
#include <hip/hip_runtime.h>

// ---------------------------------------------------------------------------
// A3TGCN2 TemporalGNN, MI355X (gfx950)
//
// Pipeline: memset(deg/cursor), k_deg, k_prep(pack), k_scan(+dinv), k_csr,
//           k_agg, k_gru
//
// R1: 12x unroll -> spill.  R2: launch_bounds VGPR cap -> spill.
// R3: pointer-passed local arrays never promoted -> named float4 X-macros,
//     weights from global (uniform -> s_load/L1-broadcast), no LDS.
// R4/R5: macro token-pasting traps (pp-numbers, member-name params).
// R6 lesson: k_gru correct (FETCH=AX only) but parallelism-starved:
//     1563 waves on 1024 SIMDs (Occupancy 9.5%, VALUBusy 55%). Fix: split
//     each node across 4 lanes (8 H-components/lane) -> 4x waves AND 3.5x
//     fewer per-lane instructions; cross-lane H broadcast via __shfl.
// ---------------------------------------------------------------------------

#define NN 50000
#define NE 800000
#define FIN 8
#define PER 12
#define HID 32
#define BATCH 2
#define FP 96                 // FIN*PER
#define BN (BATCH * NN)
#define OUTF 24               // PER*NTF

// workspace layout (float units)
#define OFF_PROBS  0          // 12
#define OFF_WPK    16         // 3 gates * 1312  ([8x32 M][32x32 Lbot][32 c])
#define GSTRIDE    1312
#define OFF_WOUT   3952       // WoutT: 24 x 32 (transposed!)
#define OFF_BOUT   4720       // 24
#define OFF_DINV   4744       // N floats
#define OFF_DEGI   54744      // N ints   (contiguous with cursor for memset)
#define OFF_CURSOR 104744     // N ints
#define OFF_ROWPTR 154744     // N+1 ints
#define OFF_COL    204752     // E ints
#define OFF_WGT    1004752    // E floats
#define OFF_AX     1804752    // 96 * B*N floats
#define WS_FLOATS  11404752   // ~45.6 MB needed

__device__ __forceinline__ float fast_exp2(float x) {
#if __has_builtin(__builtin_amdgcn_exp2f)
    return __builtin_amdgcn_exp2f(x);
#else
    return exp2f(x);
#endif
}
__device__ __forceinline__ float fast_rcp(float x) {
#if __has_builtin(__builtin_amdgcn_rcpf)
    return __builtin_amdgcn_rcpf(x);
#else
    return 1.0f / x;
#endif
}
__device__ __forceinline__ float sigm(float x) {
    return fast_rcp(1.0f + fast_exp2(-1.4426950408889634f * x));
}
__device__ __forceinline__ float tanh_fast(float x) {
    return 2.0f * fast_rcp(1.0f + fast_exp2(-2.8853900817779268f * x)) - 1.0f;
}

__global__ void k_deg(const int* __restrict__ dst, int* __restrict__ degi) {
    int e = blockIdx.x * blockDim.x + threadIdx.x;
    if (e < NE) atomicAdd(&degi[dst[e]], 1);
}

// Packs: probs, per-gate [M(8x32) | Lbot(32x32) | c(32)], WoutT (24x32), bout.
__global__ void k_prep(const float* __restrict__ att,
                       const float* __restrict__ Wz, const float* __restrict__ bz,
                       const float* __restrict__ Wr, const float* __restrict__ br,
                       const float* __restrict__ Wh, const float* __restrict__ bh,
                       const float* __restrict__ Lz, const float* __restrict__ lbz,
                       const float* __restrict__ Lr, const float* __restrict__ lbr,
                       const float* __restrict__ Lh, const float* __restrict__ lbh,
                       const float* __restrict__ Wout, const float* __restrict__ bout,
                       float* __restrict__ ws) {
    int tid = threadIdx.x;
    if (tid == 0) {
        float a[PER], m = -1e30f, s = 0.0f;
        for (int i = 0; i < PER; i++) { a[i] = att[i]; m = fmaxf(m, a[i]); }
        for (int i = 0; i < PER; i++) { a[i] = __expf(a[i] - m); s += a[i]; }
        for (int i = 0; i < PER; i++) ws[OFF_PROBS + i] = a[i] / s;
    }
    int k = tid >> 5, j = tid & 31;   // k in [0,8), j in [0,32)
    const float* Ws[3]  = { Wz, Wr, Wh };
    const float* Ls[3]  = { Lz, Lr, Lh };
    const float* bs[3]  = { bz, br, bh };
    const float* lbs[3] = { lbz, lbr, lbh };
    for (int g = 0; g < 3; g++) {
        float* wp = ws + OFF_WPK + g * GSTRIDE;
        float acc = 0.0f;
        for (int i = 0; i < HID; i++) acc += Ws[g][k * HID + i] * Ls[g][i * HID + j];
        wp[k * HID + j] = acc;
        for (int i = tid; i < 1024; i += 256) wp[256 + i] = Ls[g][1024 + i];
        if (tid < HID) {
            float c = lbs[g][tid];
            for (int i = 0; i < HID; i++) c += bs[g][i] * Ls[g][i * HID + tid];
            wp[1280 + tid] = c;
        }
    }
    // WoutT[c][i] = Wout[i][c]
    for (int idx = tid; idx < 768; idx += 256) {
        int c = idx >> 5, i = idx & 31;
        ws[OFF_WOUT + idx] = Wout[i * OUTF + c];
    }
    if (tid < OUTF) ws[OFF_BOUT + tid] = bout[tid];
}

// strip scan: 1024 threads x STRIP elements; also computes dinv. One block.
#define STRIP 49   // ceil(50000/1024)
__global__ __launch_bounds__(1024)
void k_scan(const int* __restrict__ degi, int* __restrict__ rowptr,
            float* __restrict__ dinv) {
    __shared__ int wsum[16];
    int tid = threadIdx.x;
    int lane = tid & 63, wid = tid >> 6;
    int s0 = tid * STRIP;
    int vals[STRIP];
    int sum = 0;
    #pragma unroll
    for (int i = 0; i < STRIP; i++) {
        int idx = s0 + i;
        int d = (idx < NN) ? degi[idx] : 0;
        vals[i] = d;
        sum += d;
        if (idx < NN) dinv[idx] = rsqrtf(1.0f + (float)d);
    }
    // wave-inclusive scan of per-thread sums
    int run = sum;
    #pragma unroll
    for (int off = 1; off < 64; off <<= 1) {
        int t = __shfl_up(run, off);
        if (lane >= off) run += t;
    }
    if (lane == 63) wsum[wid] = run;
    __syncthreads();
    if (wid == 0 && lane < 16) {
        int v = wsum[lane];
        #pragma unroll
        for (int off = 1; off < 16; off <<= 1) {
            int t = __shfl_up(v, off);
            if (lane >= off) v += t;
        }
        wsum[lane] = v;   // inclusive wave totals
    }
    __syncthreads();
    int base = (wid ? wsum[wid - 1] : 0) + (run - sum);  // exclusive prefix
    if (tid == 0) rowptr[0] = 0;
    #pragma unroll
    for (int i = 0; i < STRIP; i++) {
        int idx = s0 + i;
        if (idx < NN) { base += vals[i]; rowptr[idx + 1] = base; }
    }
}

__global__ void k_csr(const int* __restrict__ src, const int* __restrict__ dst,
                      const int* __restrict__ rowptr, int* __restrict__ cursor,
                      const float* __restrict__ dinv,
                      int* __restrict__ col, float* __restrict__ wgt) {
    int e = blockIdx.x * blockDim.x + threadIdx.x;
    if (e >= NE) return;
    int s = src[e], d = dst[e];
    int pos = atomicAdd(&cursor[d], 1);
    int i = rowptr[d] + pos;
    col[i] = s;
    wgt[i] = dinv[s] * dinv[d];
}

// 6 chunks of 4 floats per thread; gridDim.y = 4 covers the 96 (f,p) values
__global__ void k_agg(const float* __restrict__ x,
                      const int* __restrict__ rowptr, const int* __restrict__ col,
                      const float* __restrict__ wgt, const float* __restrict__ dinv,
                      float* __restrict__ AX) {
    int n = blockIdx.x * blockDim.x + threadIdx.x;
    if (n >= NN) return;
    int cb = blockIdx.y * 6;
    int r0 = rowptr[n], r1 = rowptr[n + 1];
    float4 a0[6], a1[6];
    #pragma unroll
    for (int cc = 0; cc < 6; cc++) {
        a0[cc] = make_float4(0.f, 0.f, 0.f, 0.f);
        a1[cc] = make_float4(0.f, 0.f, 0.f, 0.f);
    }
    for (int i = r0; i < r1; i++) {
        int s = col[i];
        float w = wgt[i];
        const float* xb0 = x + (size_t)s * FP + cb * 4;
        const float* xb1 = xb0 + (size_t)NN * FP;
        #pragma unroll
        for (int cc = 0; cc < 6; cc++) {
            float4 v0 = *(const float4*)(xb0 + cc * 4);
            float4 v1 = *(const float4*)(xb1 + cc * 4);
            a0[cc].x += w * v0.x; a0[cc].y += w * v0.y; a0[cc].z += w * v0.z; a0[cc].w += w * v0.w;
            a1[cc].x += w * v1.x; a1[cc].y += w * v1.y; a1[cc].z += w * v1.z; a1[cc].w += w * v1.w;
        }
    }
    {   // self loop: weight dinv[n]^2
        float di = dinv[n];
        float w = di * di;
        const float* xb0 = x + (size_t)n * FP + cb * 4;
        const float* xb1 = xb0 + (size_t)NN * FP;
        #pragma unroll
        for (int cc = 0; cc < 6; cc++) {
            float4 v0 = *(const float4*)(xb0 + cc * 4);
            float4 v1 = *(const float4*)(xb1 + cc * 4);
            a0[cc].x += w * v0.x; a0[cc].y += w * v0.y; a0[cc].z += w * v0.z; a0[cc].w += w * v0.w;
            a1[cc].x += w * v1.x; a1[cc].y += w * v1.y; a1[cc].z += w * v1.z; a1[cc].w += w * v1.w;
        }
    }
    #pragma unroll
    for (int cc = 0; cc < 6; cc++) {
        int q = (cb + cc) * 4;
        AX[(size_t)(q + 0) * BN + n] = a0[cc].x;
        AX[(size_t)(q + 1) * BN + n] = a0[cc].y;
        AX[(size_t)(q + 2) * BN + n] = a0[cc].z;
        AX[(size_t)(q + 3) * BN + n] = a0[cc].w;
        AX[(size_t)(q + 0) * BN + NN + n] = a1[cc].x;
        AX[(size_t)(q + 1) * BN + NN + n] = a1[cc].y;
        AX[(size_t)(q + 2) * BN + NN + n] = a1[cc].z;
        AX[(size_t)(q + 3) * BN + NN + n] = a1[cc].w;
    }
}

// ----- 4-lane-per-node GRU: 8 H-components per lane, shfl broadcast -----

#define FOR8(OP) \
    OP(0,x,0) OP(0,y,1) OP(0,z,2) OP(0,w,3) \
    OP(1,x,4) OP(1,y,5) OP(1,z,6) OP(1,w,7)

#define FOR32(OP) \
    OP(0,x,0)  OP(0,y,1)  OP(0,z,2)  OP(0,w,3) \
    OP(1,x,4)  OP(1,y,5)  OP(1,z,6)  OP(1,w,7) \
    OP(2,x,8)  OP(2,y,9)  OP(2,z,10) OP(2,w,11) \
    OP(3,x,12) OP(3,y,13) OP(3,z,14) OP(3,w,15) \
    OP(4,x,16) OP(4,y,17) OP(4,z,18) OP(4,w,19) \
    OP(5,x,20) OP(5,y,21) OP(5,z,22) OP(5,w,23) \
    OP(6,x,24) OP(6,y,25) OP(6,z,26) OP(6,w,27) \
    OP(7,x,28) OP(7,y,29) OP(7,z,30) OP(7,w,31)

// component-wise fma; param names must not be x/y/z/w (R5 lesson)
#define FMA4(dd, ss, vv) \
    dd.x = fmaf((ss), (vv).x, dd.x); dd.y = fmaf((ss), (vv).y, dd.y); \
    dd.z = fmaf((ss), (vv).z, dd.z); dd.w = fmaf((ss), (vv).w, dd.w);

// P##0,P##1 (8 floats) += a * W[ofs..ofs+7]  (per-lane W already offset by sub*8)
#define ROW8(P, a, W, ofs) do { \
    float4 u0 = *(const float4*)((W) + (ofs)); \
    float4 u1 = *(const float4*)((W) + (ofs) + 4); \
    float av = (a); \
    FMA4(P##0, av, u0) FMA4(P##1, av, u1) \
} while (0)

#define LDB8(P, W) \
    P##0 = *(const float4*)((W) + 1280); P##1 = *(const float4*)((W) + 1284);

#define GATE8_IN(P, W) \
    ROW8(P, in0.x, W, 0);   ROW8(P, in0.y, W, 32);  ROW8(P, in0.z, W, 64);  ROW8(P, in0.w, W, 96); \
    ROW8(P, in1.x, W, 128); ROW8(P, in1.y, W, 160); ROW8(P, in1.z, W, 192); ROW8(P, in1.w, W, 224);

#define GH8_O(i,c,n) ROW8(o, hf##i.c, Wg, 256 + 32*(n));
#define GH8_Z(i,c,n) ROW8(z, hf##i.c, Wg, 256 + 32*(n));
#define GH8_T(i,c,n) ROW8(t, hf##i.c, Wg, 256 + 32*(n));

#define ZERO8(i,c,n) h##i.c = 0.0f; ac##i.c = 0.0f;
#define HR8(i,c,n)   o##i.c = sigm(o##i.c) * h##i.c;
#define TANH8(i,c,n) t##i.c = tanh_fast(t##i.c);
#define UPD8(i,c,n)  { float Zv = sigm(z##i.c); \
                       h##i.c = fmaf(Zv, h##i.c - t##i.c, t##i.c); \
                       ac##i.c = fmaf(pp, h##i.c, ac##i.c); }
#define RELU8(i,c,n) ac##i.c = fmaxf(ac##i.c, 0.0f);

// broadcast a float4 from lane (lb+kb) of the node's 4-lane group
#define SHUFV(dst, srcv, kb) \
    dst.x = __shfl(srcv.x, lb + (kb)); dst.y = __shfl(srcv.y, lb + (kb)); \
    dst.z = __shfl(srcv.z, lb + (kb)); dst.w = __shfl(srcv.w, lb + (kb));

#define SHUF_ALL(S) \
    SHUFV(hf0, S##0, 0) SHUFV(hf1, S##1, 0) SHUFV(hf2, S##0, 1) SHUFV(hf3, S##1, 1) \
    SHUFV(hf4, S##0, 2) SHUFV(hf5, S##1, 2) SHUFV(hf6, S##0, 3) SHUFV(hf7, S##1, 3)

#define DOT32(i,c,n) qv = fmaf(hf##i.c, wr##i.c, qv);

#define OCOL(cidx) do { \
    float4 wr0 = *(const float4*)(WOTl + (cidx)*32); \
    float4 wr1 = *(const float4*)(WOTl + (cidx)*32 + 4); \
    float4 wr2 = *(const float4*)(WOTl + (cidx)*32 + 8); \
    float4 wr3 = *(const float4*)(WOTl + (cidx)*32 + 12); \
    float4 wr4 = *(const float4*)(WOTl + (cidx)*32 + 16); \
    float4 wr5 = *(const float4*)(WOTl + (cidx)*32 + 20); \
    float4 wr6 = *(const float4*)(WOTl + (cidx)*32 + 24); \
    float4 wr7 = *(const float4*)(WOTl + (cidx)*32 + 28); \
    float qv = wp[OFF_BOUT + sub * 6 + (cidx)]; \
    FOR32(DOT32) \
    op[cidx] = qv; \
} while (0)

__global__ __launch_bounds__(256)
void k_gru(const float* __restrict__ AX, const float* __restrict__ wp,
           float* __restrict__ out) {
    int tid = threadIdx.x;
    int lane = tid & 63;
    int sub = lane & 3;                       // which 8-slice of HID
    int lb = lane & ~3;                       // group base lane
    int g = blockIdx.x * 64 + (tid >> 2);     // node (b*N+n); 64 nodes/block
    if (g >= BN) return;

    const float* WZl = wp + OFF_WPK + sub * 8;
    const float* WRl = wp + OFF_WPK + GSTRIDE + sub * 8;
    const float* WHl = wp + OFF_WPK + 2 * GSTRIDE + sub * 8;

    float4 h0, h1, ac0, ac1, o0, o1, t0, t1, z0, z1, in0, in1;
    float4 hf0, hf1, hf2, hf3, hf4, hf5, hf6, hf7;
    FOR8(ZERO8)

    #pragma unroll 1
    for (int p = 0; p < PER; p++) {
        const float* axp = AX + (size_t)p * BN + g;
        in0.x = axp[0];
        in0.y = axp[(size_t)1 * PER * BN];
        in0.z = axp[(size_t)2 * PER * BN];
        in0.w = axp[(size_t)3 * PER * BN];
        in1.x = axp[(size_t)4 * PER * BN];
        in1.y = axp[(size_t)5 * PER * BN];
        in1.z = axp[(size_t)6 * PER * BN];
        in1.w = axp[(size_t)7 * PER * BN];
        float pp = wp[OFF_PROBS + p];

        SHUF_ALL(h)                                       // hf = full H
        // R gate -> o = sigm(R)*h_own
        { const float* Wg = WRl; LDB8(o, Wg); GATE8_IN(o, Wg); FOR32(GH8_O) }
        FOR8(HR8)
        // Z gate (uses H) -> z
        { const float* Wg = WZl; LDB8(z, Wg); GATE8_IN(z, Wg); FOR32(GH8_Z) }
        SHUF_ALL(o)                                       // hf = full H*R
        // T gate -> t = tanh(T)
        { const float* Wg = WHl; LDB8(t, Wg); GATE8_IN(t, Wg); FOR32(GH8_T) }
        FOR8(TANH8)
        FOR8(UPD8)
    }

    // epilogue: out[g][sub*6 .. sub*6+6) = relu(acc) @ WoutT + bout
    FOR8(RELU8)
    SHUF_ALL(ac)                                          // hf = full relu(acc)
    const float* WOTl = wp + OFF_WOUT + sub * 6 * 32;
    float* op = out + (size_t)g * OUTF + sub * 6;
    OCOL(0); OCOL(1); OCOL(2); OCOL(3); OCOL(4); OCOL(5);
}

extern "C" void kernel_launch(void* const* d_in, const int* in_sizes, int n_in,
                              void* d_out, int out_size, void* d_ws, size_t ws_size,
                              hipStream_t stream) {
    if (ws_size < (size_t)WS_FLOATS * sizeof(float)) return;  // need ~45.6 MB scratch

    const float* x    = (const float*)d_in[0];
    const int*   ei   = (const int*)d_in[1];
    const float* att  = (const float*)d_in[2];
    const float* Wz   = (const float*)d_in[3];
    const float* bz   = (const float*)d_in[4];
    const float* Wr   = (const float*)d_in[5];
    const float* br   = (const float*)d_in[6];
    const float* Wh   = (const float*)d_in[7];
    const float* bh   = (const float*)d_in[8];
    const float* Lz   = (const float*)d_in[9];
    const float* lbz  = (const float*)d_in[10];
    const float* Lr   = (const float*)d_in[11];
    const float* lbr  = (const float*)d_in[12];
    const float* Lh   = (const float*)d_in[13];
    const float* lbh  = (const float*)d_in[14];
    const float* Wout = (const float*)d_in[15];
    const float* bout = (const float*)d_in[16];
    float* out = (float*)d_out;
    float* ws  = (float*)d_ws;

    const int* src = ei;
    const int* dst = ei + NE;

    float* dinv   = ws + OFF_DINV;
    int*   degi   = (int*)(ws + OFF_DEGI);
    int*   cursor = (int*)(ws + OFF_CURSOR);
    int*   rowptr = (int*)(ws + OFF_ROWPTR);
    int*   col    = (int*)(ws + OFF_COL);
    float* wgt    = ws + OFF_WGT;
    float* AX     = ws + OFF_AX;

    // degi and cursor are contiguous: one async memset clears both
    hipMemsetAsync(degi, 0, 2 * (size_t)NN * sizeof(int), stream);
    k_deg<<<(NE + 255) / 256, 256, 0, stream>>>(dst, degi);
    k_prep<<<1, 256, 0, stream>>>(att, Wz, bz, Wr, br, Wh, bh,
                                  Lz, lbz, Lr, lbr, Lh, lbh, Wout, bout, ws);
    k_scan<<<1, 1024, 0, stream>>>(degi, rowptr, dinv);
    k_csr<<<(NE + 255) / 256, 256, 0, stream>>>(src, dst, rowptr, cursor, dinv, col, wgt);
    dim3 gAgg((NN + 255) / 256, 4);
    k_agg<<<gAgg, 256, 0, stream>>>(x, rowptr, col, wgt, dinv, AX);
    k_gru<<<(BN + 63) / 64, 256, 0, stream>>>(AX, ws, out);
}